// Round 3
// baseline (618.329 us; speedup 1.0000x reference)
//
#include <hip/hip_runtime.h>
#include <hip/hip_bf16.h>

#define C 128
#define RBFD 20
#define NATOMS 50000
#define SCAN_CHUNK 1024

// ---------------------------------------------------------------------------
// Kernel 1: transpose W1, W2 (C x C, row-major [out][in]) into [in][out]
// ---------------------------------------------------------------------------
__global__ void transpose_w_kernel(const float* __restrict__ W1,
                                   const float* __restrict__ W2,
                                   float* __restrict__ W1T,
                                   float* __restrict__ W2T) {
    int t = blockIdx.x * blockDim.x + threadIdx.x;
    if (t < C * C) {
        int k = t / C;   // in-channel
        int c = t % C;   // out-channel
        W1T[t] = W1[c * C + k];
        W2T[t] = W2[c * C + k];
    }
}

// ---------------------------------------------------------------------------
// CSR construction: histogram -> hierarchical exclusive scan -> perm fill
// ---------------------------------------------------------------------------
__global__ __launch_bounds__(256) void histogram_kernel(
    const int* __restrict__ idx, int* __restrict__ count, int E)
{
    int e = blockIdx.x * blockDim.x + threadIdx.x;
    if (e < E) atomicAdd(&count[idx[e]], 1);
}

__global__ __launch_bounds__(256) void scan_partials_kernel(
    const int* __restrict__ count, int* __restrict__ partial, int n)
{
    __shared__ int sm[256];
    const int start = blockIdx.x * SCAN_CHUNK;
    int s = 0;
    for (int i = threadIdx.x; i < SCAN_CHUNK; i += 256) {
        int g = start + i;
        if (g < n) s += count[g];
    }
    sm[threadIdx.x] = s;
    __syncthreads();
    for (int off = 128; off > 0; off >>= 1) {
        if (threadIdx.x < off) sm[threadIdx.x] += sm[threadIdx.x + off];
        __syncthreads();
    }
    if (threadIdx.x == 0) partial[blockIdx.x] = sm[0];
}

__global__ void scan_chunkbase_kernel(int* __restrict__ partial,
                                      int* __restrict__ base,
                                      int nchunks, int n)
{
    if (threadIdx.x == 0 && blockIdx.x == 0) {
        int run = 0;
        for (int k = 0; k < nchunks; ++k) {
            int t = partial[k];
            partial[k] = run;
            run += t;
        }
        base[n] = run;
    }
}

__global__ __launch_bounds__(1024) void scan_apply_kernel(
    const int* __restrict__ count, const int* __restrict__ chunk_base,
    int* __restrict__ base, int* __restrict__ cursor, int n)
{
    __shared__ int sm[SCAN_CHUNK];
    const int t = threadIdx.x;
    const int i = blockIdx.x * SCAN_CHUNK + t;
    int v = (i < n) ? count[i] : 0;
    sm[t] = v;
    __syncthreads();
    for (int off = 1; off < SCAN_CHUNK; off <<= 1) {
        int tmp = (t >= off) ? sm[t - off] : 0;
        __syncthreads();
        sm[t] += tmp;
        __syncthreads();
    }
    if (i < n) {
        int excl = sm[t] - v + chunk_base[blockIdx.x];
        base[i] = excl;
        cursor[i] = excl;
    }
}

__global__ __launch_bounds__(256) void fill_perm_kernel(
    const int* __restrict__ idx, int* __restrict__ cursor,
    int* __restrict__ perm, int E)
{
    int e = blockIdx.x * blockDim.x + threadIdx.x;
    if (e < E) {
        int a = idx[e];
        int pos = atomicAdd(&cursor[a], 1);
        perm[pos] = e;
    }
}

// ---------------------------------------------------------------------------
// Gather kernel, 4-edge unrolled for memory-level parallelism.
// 2 atoms per 256-thread block, thread = channel.
// ---------------------------------------------------------------------------
__device__ __forceinline__ float rbf_dot(const float4* __restrict__ r4,
                                         const float* __restrict__ w,
                                         float bias)
{
    float4 rv0 = r4[0], rv1 = r4[1], rv2 = r4[2], rv3 = r4[3], rv4 = r4[4];
    float f = bias;
    f = fmaf(rv0.x, w[0], f);  f = fmaf(rv0.y, w[1], f);
    f = fmaf(rv0.z, w[2], f);  f = fmaf(rv0.w, w[3], f);
    f = fmaf(rv1.x, w[4], f);  f = fmaf(rv1.y, w[5], f);
    f = fmaf(rv1.z, w[6], f);  f = fmaf(rv1.w, w[7], f);
    f = fmaf(rv2.x, w[8], f);  f = fmaf(rv2.y, w[9], f);
    f = fmaf(rv2.z, w[10], f); f = fmaf(rv2.w, w[11], f);
    f = fmaf(rv3.x, w[12], f); f = fmaf(rv3.y, w[13], f);
    f = fmaf(rv3.z, w[14], f); f = fmaf(rv3.w, w[15], f);
    f = fmaf(rv4.x, w[16], f); f = fmaf(rv4.y, w[17], f);
    f = fmaf(rv4.z, w[18], f); f = fmaf(rv4.w, w[19], f);
    return f;
}

__global__ __launch_bounds__(256) void gather_kernel(
    const float* __restrict__ x,       // [E][C]
    const float* __restrict__ rbf,     // [E][RBFD]
    const float* __restrict__ env,     // [E]
    const int*   __restrict__ perm,    // [E]
    const int*   __restrict__ base,    // [N+1]
    const float* __restrict__ Wrbf,    // [C][RBFD]
    const float* __restrict__ brbf,    // [C]
    float* __restrict__ acc,           // [N][C]
    int natoms)
{
    const int tid = threadIdx.x;
    const int c   = tid & (C - 1);
    const int a   = blockIdx.x * 2 + (tid >> 7);
    if (a >= natoms) return;

    float w[RBFD];
#pragma unroll
    for (int r = 0; r < RBFD; ++r) w[r] = Wrbf[c * RBFD + r];
    const float bias = brbf[c];

    const int s0 = base[a], s1 = base[a + 1];
    float sum = 0.0f;

    int p = s0;
    // ---- 4-edge unrolled main loop: batch independent loads ----
    for (; p + 4 <= s1; p += 4) {
        const int e0 = perm[p + 0];
        const int e1 = perm[p + 1];
        const int e2 = perm[p + 2];
        const int e3 = perm[p + 3];

        const float4* r0 = reinterpret_cast<const float4*>(rbf + (size_t)e0 * RBFD);
        const float4* r1 = reinterpret_cast<const float4*>(rbf + (size_t)e1 * RBFD);
        const float4* r2 = reinterpret_cast<const float4*>(rbf + (size_t)e2 * RBFD);
        const float4* r3 = reinterpret_cast<const float4*>(rbf + (size_t)e3 * RBFD);

        // independent loads: x rows, env, rbf rows — all issued before use
        const float x0 = x[(size_t)e0 * C + c];
        const float x1 = x[(size_t)e1 * C + c];
        const float x2 = x[(size_t)e2 * C + c];
        const float x3 = x[(size_t)e3 * C + c];
        const float v0 = env[e0];
        const float v1 = env[e1];
        const float v2 = env[e2];
        const float v3 = env[e3];

        const float f0 = rbf_dot(r0, w, bias);
        const float f1 = rbf_dot(r1, w, bias);
        const float f2 = rbf_dot(r2, w, bias);
        const float f3 = rbf_dot(r3, w, bias);

        sum = fmaf(f0 * v0, x0, sum);
        sum = fmaf(f1 * v1, x1, sum);
        sum = fmaf(f2 * v2, x2, sum);
        sum = fmaf(f3 * v3, x3, sum);
    }
    // ---- remainder ----
    for (; p < s1; ++p) {
        const int e = perm[p];
        const float4* r4 = reinterpret_cast<const float4*>(rbf + (size_t)e * RBFD);
        const float f = rbf_dot(r4, w, bias);
        sum = fmaf(f * env[e], x[(size_t)e * C + c], sum);
    }
    acc[(size_t)a * C + c] = sum;
}

// ---------------------------------------------------------------------------
// Fused MLP head (unchanged).
// ---------------------------------------------------------------------------
__device__ __forceinline__ float silu_f(float v) {
    return v * (1.0f / (1.0f + __expf(-v)));
}

__global__ __launch_bounds__(256) void mlp_head_kernel(
    const float* __restrict__ acc,   // [N][C]
    const float* __restrict__ W1T,   // [C][C]  (k-major)
    const float* __restrict__ b1,    // [C]
    const float* __restrict__ W2T,   // [C][C]
    const float* __restrict__ b2,    // [C]
    const float* __restrict__ W3,    // [1][C]
    const float* __restrict__ b3,    // [1]
    float* __restrict__ out,         // [N]
    int natoms)
{
    __shared__ float As[C][C + 1];

    const int tid = threadIdx.x;
    const int a0  = blockIdx.x * C;
    const int tc  = tid & 15;
    const int ta  = tid >> 4;
    const int abase = ta * 8;
    const int cbase = tc * 8;

    {
        const int sub = tid >> 7;
        const int k   = tid & 127;
        for (int pair = 0; pair < 64; ++pair) {
            const int al = pair * 2 + sub;
            const int a  = a0 + al;
            float v = (a < natoms) ? acc[(size_t)a * C + k] : 0.0f;
            As[k][al] = v;
        }
    }
    __syncthreads();

    float r[8][8];

    // layer 1
#pragma unroll
    for (int i = 0; i < 8; ++i)
#pragma unroll
        for (int j = 0; j < 8; ++j) r[i][j] = 0.0f;

#pragma unroll 2
    for (int k = 0; k < C; ++k) {
        float4 bq0 = *reinterpret_cast<const float4*>(W1T + k * C + cbase);
        float4 bq1 = *reinterpret_cast<const float4*>(W1T + k * C + cbase + 4);
        float bv[8] = {bq0.x, bq0.y, bq0.z, bq0.w, bq1.x, bq1.y, bq1.z, bq1.w};
        float av[8];
#pragma unroll
        for (int i = 0; i < 8; ++i) av[i] = As[k][abase + i];
#pragma unroll
        for (int i = 0; i < 8; ++i)
#pragma unroll
            for (int j = 0; j < 8; ++j) r[i][j] = fmaf(av[i], bv[j], r[i][j]);
    }

    __syncthreads();
    {
        float bb[8];
#pragma unroll
        for (int j = 0; j < 8; ++j) bb[j] = b1[cbase + j];
#pragma unroll
        for (int i = 0; i < 8; ++i)
#pragma unroll
            for (int j = 0; j < 8; ++j)
                As[cbase + j][abase + i] = silu_f(r[i][j] + bb[j]);
    }
    __syncthreads();

    // layer 2
#pragma unroll
    for (int i = 0; i < 8; ++i)
#pragma unroll
        for (int j = 0; j < 8; ++j) r[i][j] = 0.0f;

#pragma unroll 2
    for (int k = 0; k < C; ++k) {
        float4 bq0 = *reinterpret_cast<const float4*>(W2T + k * C + cbase);
        float4 bq1 = *reinterpret_cast<const float4*>(W2T + k * C + cbase + 4);
        float bv[8] = {bq0.x, bq0.y, bq0.z, bq0.w, bq1.x, bq1.y, bq1.z, bq1.w};
        float av[8];
#pragma unroll
        for (int i = 0; i < 8; ++i) av[i] = As[k][abase + i];
#pragma unroll
        for (int i = 0; i < 8; ++i)
#pragma unroll
            for (int j = 0; j < 8; ++j) r[i][j] = fmaf(av[i], bv[j], r[i][j]);
    }

    __syncthreads();

    // final: silu(.. + b2) . W3
    {
        float bb[8], w3v[8];
#pragma unroll
        for (int j = 0; j < 8; ++j) bb[j] = b2[cbase + j];
        float4 wq0 = *reinterpret_cast<const float4*>(W3 + cbase);
        float4 wq1 = *reinterpret_cast<const float4*>(W3 + cbase + 4);
        w3v[0]=wq0.x; w3v[1]=wq0.y; w3v[2]=wq0.z; w3v[3]=wq0.w;
        w3v[4]=wq1.x; w3v[5]=wq1.y; w3v[6]=wq1.z; w3v[7]=wq1.w;

#pragma unroll
        for (int i = 0; i < 8; ++i) {
            float p = 0.0f;
#pragma unroll
            for (int j = 0; j < 8; ++j)
                p = fmaf(silu_f(r[i][j] + bb[j]), w3v[j], p);
            As[abase + i][tc] = p;
        }
    }
    __syncthreads();

    if (tid < C) {
        const int a = a0 + tid;
        if (a < natoms) {
            float s = 0.0f;
#pragma unroll
            for (int t = 0; t < 16; ++t) s += As[tid][t];
            out[a] = s + b3[0];
        }
    }
}

// ---------------------------------------------------------------------------
extern "C" void kernel_launch(void* const* d_in, const int* in_sizes, int n_in,
                              void* d_out, int out_size, void* d_ws, size_t ws_size,
                              hipStream_t stream) {
    const float* x      = (const float*)d_in[0];
    const float* rbf    = (const float*)d_in[1];
    const float* env    = (const float*)d_in[2];
    const int*   idx    = (const int*)  d_in[3];
    const float* Wrbf   = (const float*)d_in[5];
    const float* brbf   = (const float*)d_in[6];
    const float* W1     = (const float*)d_in[7];
    const float* b1     = (const float*)d_in[8];
    const float* W2     = (const float*)d_in[9];
    const float* b2     = (const float*)d_in[10];
    const float* W3     = (const float*)d_in[11];
    const float* b3     = (const float*)d_in[12];
    float*       out    = (float*)d_out;

    const int E = in_sizes[0] / C;        // 800000
    const int N = NATOMS;                 // 50000
    const int nchunks = (N + SCAN_CHUNK - 1) / SCAN_CHUNK;   // 49

    // workspace layout
    float* acc     = (float*)d_ws;                    // N*C
    float* W1T     = acc + (size_t)N * C;             // C*C
    float* W2T     = W1T + C * C;                     // C*C
    int*   count   = (int*)(W2T + C * C);             // N
    int*   base    = count + N;                       // N+1
    int*   cursor  = base + (N + 1);                  // N
    int*   partial = cursor + N;                      // 64
    int*   perm    = partial + 64;                    // E

    hipMemsetAsync(count, 0, (size_t)N * sizeof(int), stream);

    transpose_w_kernel<<<(C * C + 255) / 256, 256, 0, stream>>>(W1, W2, W1T, W2T);

    histogram_kernel<<<(E + 255) / 256, 256, 0, stream>>>(idx, count, E);
    scan_partials_kernel<<<nchunks, 256, 0, stream>>>(count, partial, N);
    scan_chunkbase_kernel<<<1, 64, 0, stream>>>(partial, base, nchunks, N);
    scan_apply_kernel<<<nchunks, SCAN_CHUNK, 0, stream>>>(count, partial, base, cursor, N);
    fill_perm_kernel<<<(E + 255) / 256, 256, 0, stream>>>(idx, cursor, perm, E);

    gather_kernel<<<(N + 1) / 2, 256, 0, stream>>>(x, rbf, env, perm, base,
                                                   Wrbf, brbf, acc, N);

    const int tiles = (N + C - 1) / C;
    mlp_head_kernel<<<tiles, 256, 0, stream>>>(acc, W1T, b1, W2T, b2, W3, b3, out, N);
}

// Round 4
// 379.340 us; speedup vs baseline: 1.6300x; 1.6300x over previous
//
#include <hip/hip_runtime.h>
#include <hip/hip_bf16.h>

#define C 128
#define RBFD 20
#define NATOMS 50000
#define SCAN_CHUNK 1024
#define EDGE_CHUNK 64

// ---------------------------------------------------------------------------
// Kernel 1: transpose W1, W2 (C x C, row-major [out][in]) into [in][out]
// ---------------------------------------------------------------------------
__global__ void transpose_w_kernel(const float* __restrict__ W1,
                                   const float* __restrict__ W2,
                                   float* __restrict__ W1T,
                                   float* __restrict__ W2T) {
    int t = blockIdx.x * blockDim.x + threadIdx.x;
    if (t < C * C) {
        int k = t / C;   // in-channel
        int c = t % C;   // out-channel
        W1T[t] = W1[c * C + k];
        W2T[t] = W2[c * C + k];
    }
}

// ---------------------------------------------------------------------------
// CSR construction: histogram -> hierarchical exclusive scan -> perm fill
// ---------------------------------------------------------------------------
__global__ __launch_bounds__(256) void histogram_kernel(
    const int* __restrict__ idx, int* __restrict__ count, int E)
{
    int e = blockIdx.x * blockDim.x + threadIdx.x;
    if (e < E) atomicAdd(&count[idx[e]], 1);
}

__global__ __launch_bounds__(256) void scan_partials_kernel(
    const int* __restrict__ count, int* __restrict__ partial, int n)
{
    __shared__ int sm[256];
    const int start = blockIdx.x * SCAN_CHUNK;
    int s = 0;
    for (int i = threadIdx.x; i < SCAN_CHUNK; i += 256) {
        int g = start + i;
        if (g < n) s += count[g];
    }
    sm[threadIdx.x] = s;
    __syncthreads();
    for (int off = 128; off > 0; off >>= 1) {
        if (threadIdx.x < off) sm[threadIdx.x] += sm[threadIdx.x + off];
        __syncthreads();
    }
    if (threadIdx.x == 0) partial[blockIdx.x] = sm[0];
}

__global__ void scan_chunkbase_kernel(int* __restrict__ partial,
                                      int* __restrict__ base,
                                      int nchunks, int n)
{
    if (threadIdx.x == 0 && blockIdx.x == 0) {
        int run = 0;
        for (int k = 0; k < nchunks; ++k) {
            int t = partial[k];
            partial[k] = run;
            run += t;
        }
        base[n] = run;
    }
}

__global__ __launch_bounds__(1024) void scan_apply_kernel(
    const int* __restrict__ count, const int* __restrict__ chunk_base,
    int* __restrict__ base, int* __restrict__ cursor, int n)
{
    __shared__ int sm[SCAN_CHUNK];
    const int t = threadIdx.x;
    const int i = blockIdx.x * SCAN_CHUNK + t;
    int v = (i < n) ? count[i] : 0;
    sm[t] = v;
    __syncthreads();
    for (int off = 1; off < SCAN_CHUNK; off <<= 1) {
        int tmp = (t >= off) ? sm[t - off] : 0;
        __syncthreads();
        sm[t] += tmp;
        __syncthreads();
    }
    if (i < n) {
        int excl = sm[t] - v + chunk_base[blockIdx.x];
        base[i] = excl;
        cursor[i] = excl;
    }
}

__global__ __launch_bounds__(256) void fill_perm_kernel(
    const int* __restrict__ idx, int* __restrict__ cursor,
    int* __restrict__ perm, int E)
{
    int e = blockIdx.x * blockDim.x + threadIdx.x;
    if (e < E) {
        int a = idx[e];
        int pos = atomicAdd(&cursor[a], 1);
        perm[pos] = e;
    }
}

// ---------------------------------------------------------------------------
// Gather kernel v3: one atom per 128-thread block (thread = channel).
// Chunk of up to 64 edge indices + envelopes staged in LDS by parallel,
// independent loads (kills the perm->data pointer chase).  Main loop is
// 4-edge unrolled with clamp+zero-mask predication so the four load->fma
// chains are architecturally independent.
// ---------------------------------------------------------------------------
__device__ __forceinline__ float rbf_dot(const float4* __restrict__ r4,
                                         const float* __restrict__ w,
                                         float bias)
{
    float4 rv0 = r4[0], rv1 = r4[1], rv2 = r4[2], rv3 = r4[3], rv4 = r4[4];
    float f = bias;
    f = fmaf(rv0.x, w[0], f);  f = fmaf(rv0.y, w[1], f);
    f = fmaf(rv0.z, w[2], f);  f = fmaf(rv0.w, w[3], f);
    f = fmaf(rv1.x, w[4], f);  f = fmaf(rv1.y, w[5], f);
    f = fmaf(rv1.z, w[6], f);  f = fmaf(rv1.w, w[7], f);
    f = fmaf(rv2.x, w[8], f);  f = fmaf(rv2.y, w[9], f);
    f = fmaf(rv2.z, w[10], f); f = fmaf(rv2.w, w[11], f);
    f = fmaf(rv3.x, w[12], f); f = fmaf(rv3.y, w[13], f);
    f = fmaf(rv3.z, w[14], f); f = fmaf(rv3.w, w[15], f);
    f = fmaf(rv4.x, w[16], f); f = fmaf(rv4.y, w[17], f);
    f = fmaf(rv4.z, w[18], f); f = fmaf(rv4.w, w[19], f);
    return f;
}

__global__ __launch_bounds__(128) void gather_kernel(
    const float* __restrict__ x,       // [E][C]
    const float* __restrict__ rbf,     // [E][RBFD]
    const float* __restrict__ env,     // [E]
    const int*   __restrict__ perm,    // [E]
    const int*   __restrict__ base,    // [N+1]
    const float* __restrict__ Wrbf,    // [C][RBFD]
    const float* __restrict__ brbf,    // [C]
    float* __restrict__ acc,           // [N][C]
    int natoms)
{
    __shared__ int   e_s[EDGE_CHUNK];
    __shared__ float env_s[EDGE_CHUNK];

    const int tid = threadIdx.x;      // 0..127, = channel
    const int a   = blockIdx.x;
    if (a >= natoms) return;

    float w[RBFD];
#pragma unroll
    for (int r = 0; r < RBFD; ++r) w[r] = Wrbf[tid * RBFD + r];
    const float bias = brbf[tid];

    const int s0 = base[a], s1 = base[a + 1];
    float sum = 0.0f;

    for (int chunk = s0; chunk < s1; chunk += EDGE_CHUNK) {
        const int cnt = min(EDGE_CHUNK, s1 - chunk);
        __syncthreads();   // protect LDS from previous chunk's readers
        if (tid < cnt) {
            const int e = perm[chunk + tid];
            e_s[tid]   = e;
            env_s[tid] = env[e];
        }
        __syncthreads();

        // 4 predicated, independent edges per iteration
        for (int r = 0; r < cnt; r += 4) {
            int   rr0 = r,     rr1 = r + 1, rr2 = r + 2, rr3 = r + 3;
            bool  ok1 = rr1 < cnt, ok2 = rr2 < cnt, ok3 = rr3 < cnt;
            int   e0 = e_s[rr0];
            int   e1 = e_s[ok1 ? rr1 : 0];
            int   e2 = e_s[ok2 ? rr2 : 0];
            int   e3 = e_s[ok3 ? rr3 : 0];
            float m0 = env_s[rr0];
            float m1 = ok1 ? env_s[rr1] : 0.0f;
            float m2 = ok2 ? env_s[rr2] : 0.0f;
            float m3 = ok3 ? env_s[rr3] : 0.0f;

            const float4* r40 = reinterpret_cast<const float4*>(rbf + (size_t)e0 * RBFD);
            const float4* r41 = reinterpret_cast<const float4*>(rbf + (size_t)e1 * RBFD);
            const float4* r42 = reinterpret_cast<const float4*>(rbf + (size_t)e2 * RBFD);
            const float4* r43 = reinterpret_cast<const float4*>(rbf + (size_t)e3 * RBFD);

            const float x0 = x[(size_t)e0 * C + tid];
            const float x1 = x[(size_t)e1 * C + tid];
            const float x2 = x[(size_t)e2 * C + tid];
            const float x3 = x[(size_t)e3 * C + tid];

            const float f0 = rbf_dot(r40, w, bias);
            const float f1 = rbf_dot(r41, w, bias);
            const float f2 = rbf_dot(r42, w, bias);
            const float f3 = rbf_dot(r43, w, bias);

            sum = fmaf(f0 * m0, x0, sum);
            sum = fmaf(f1 * m1, x1, sum);
            sum = fmaf(f2 * m2, x2, sum);
            sum = fmaf(f3 * m3, x3, sum);
        }
    }
    acc[(size_t)a * C + tid] = sum;
}

// ---------------------------------------------------------------------------
// Fused MLP head (unchanged).
// ---------------------------------------------------------------------------
__device__ __forceinline__ float silu_f(float v) {
    return v * (1.0f / (1.0f + __expf(-v)));
}

__global__ __launch_bounds__(256) void mlp_head_kernel(
    const float* __restrict__ acc,   // [N][C]
    const float* __restrict__ W1T,   // [C][C]  (k-major)
    const float* __restrict__ b1,    // [C]
    const float* __restrict__ W2T,   // [C][C]
    const float* __restrict__ b2,    // [C]
    const float* __restrict__ W3,    // [1][C]
    const float* __restrict__ b3,    // [1]
    float* __restrict__ out,         // [N]
    int natoms)
{
    __shared__ float As[C][C + 1];

    const int tid = threadIdx.x;
    const int a0  = blockIdx.x * C;
    const int tc  = tid & 15;
    const int ta  = tid >> 4;
    const int abase = ta * 8;
    const int cbase = tc * 8;

    {
        const int sub = tid >> 7;
        const int k   = tid & 127;
        for (int pair = 0; pair < 64; ++pair) {
            const int al = pair * 2 + sub;
            const int a  = a0 + al;
            float v = (a < natoms) ? acc[(size_t)a * C + k] : 0.0f;
            As[k][al] = v;
        }
    }
    __syncthreads();

    float r[8][8];

    // layer 1
#pragma unroll
    for (int i = 0; i < 8; ++i)
#pragma unroll
        for (int j = 0; j < 8; ++j) r[i][j] = 0.0f;

#pragma unroll 2
    for (int k = 0; k < C; ++k) {
        float4 bq0 = *reinterpret_cast<const float4*>(W1T + k * C + cbase);
        float4 bq1 = *reinterpret_cast<const float4*>(W1T + k * C + cbase + 4);
        float bv[8] = {bq0.x, bq0.y, bq0.z, bq0.w, bq1.x, bq1.y, bq1.z, bq1.w};
        float av[8];
#pragma unroll
        for (int i = 0; i < 8; ++i) av[i] = As[k][abase + i];
#pragma unroll
        for (int i = 0; i < 8; ++i)
#pragma unroll
            for (int j = 0; j < 8; ++j) r[i][j] = fmaf(av[i], bv[j], r[i][j]);
    }

    __syncthreads();
    {
        float bb[8];
#pragma unroll
        for (int j = 0; j < 8; ++j) bb[j] = b1[cbase + j];
#pragma unroll
        for (int i = 0; i < 8; ++i)
#pragma unroll
            for (int j = 0; j < 8; ++j)
                As[cbase + j][abase + i] = silu_f(r[i][j] + bb[j]);
    }
    __syncthreads();

    // layer 2
#pragma unroll
    for (int i = 0; i < 8; ++i)
#pragma unroll
        for (int j = 0; j < 8; ++j) r[i][j] = 0.0f;

#pragma unroll 2
    for (int k = 0; k < C; ++k) {
        float4 bq0 = *reinterpret_cast<const float4*>(W2T + k * C + cbase);
        float4 bq1 = *reinterpret_cast<const float4*>(W2T + k * C + cbase + 4);
        float bv[8] = {bq0.x, bq0.y, bq0.z, bq0.w, bq1.x, bq1.y, bq1.z, bq1.w};
        float av[8];
#pragma unroll
        for (int i = 0; i < 8; ++i) av[i] = As[k][abase + i];
#pragma unroll
        for (int i = 0; i < 8; ++i)
#pragma unroll
            for (int j = 0; j < 8; ++j) r[i][j] = fmaf(av[i], bv[j], r[i][j]);
    }

    __syncthreads();

    // final: silu(.. + b2) . W3
    {
        float bb[8], w3v[8];
#pragma unroll
        for (int j = 0; j < 8; ++j) bb[j] = b2[cbase + j];
        float4 wq0 = *reinterpret_cast<const float4*>(W3 + cbase);
        float4 wq1 = *reinterpret_cast<const float4*>(W3 + cbase + 4);
        w3v[0]=wq0.x; w3v[1]=wq0.y; w3v[2]=wq0.z; w3v[3]=wq0.w;
        w3v[4]=wq1.x; w3v[5]=wq1.y; w3v[6]=wq1.z; w3v[7]=wq1.w;

#pragma unroll
        for (int i = 0; i < 8; ++i) {
            float p = 0.0f;
#pragma unroll
            for (int j = 0; j < 8; ++j)
                p = fmaf(silu_f(r[i][j] + bb[j]), w3v[j], p);
            As[abase + i][tc] = p;
        }
    }
    __syncthreads();

    if (tid < C) {
        const int a = a0 + tid;
        if (a < natoms) {
            float s = 0.0f;
#pragma unroll
            for (int t = 0; t < 16; ++t) s += As[tid][t];
            out[a] = s + b3[0];
        }
    }
}

// ---------------------------------------------------------------------------
extern "C" void kernel_launch(void* const* d_in, const int* in_sizes, int n_in,
                              void* d_out, int out_size, void* d_ws, size_t ws_size,
                              hipStream_t stream) {
    const float* x      = (const float*)d_in[0];
    const float* rbf    = (const float*)d_in[1];
    const float* env    = (const float*)d_in[2];
    const int*   idx    = (const int*)  d_in[3];
    const float* Wrbf   = (const float*)d_in[5];
    const float* brbf   = (const float*)d_in[6];
    const float* W1     = (const float*)d_in[7];
    const float* b1     = (const float*)d_in[8];
    const float* W2     = (const float*)d_in[9];
    const float* b2     = (const float*)d_in[10];
    const float* W3     = (const float*)d_in[11];
    const float* b3     = (const float*)d_in[12];
    float*       out    = (float*)d_out;

    const int E = in_sizes[0] / C;        // 800000
    const int N = NATOMS;                 // 50000
    const int nchunks = (N + SCAN_CHUNK - 1) / SCAN_CHUNK;   // 49

    // workspace layout
    float* acc     = (float*)d_ws;                    // N*C
    float* W1T     = acc + (size_t)N * C;             // C*C
    float* W2T     = W1T + C * C;                     // C*C
    int*   count   = (int*)(W2T + C * C);             // N
    int*   base    = count + N;                       // N+1
    int*   cursor  = base + (N + 1);                  // N
    int*   partial = cursor + N;                      // 64
    int*   perm    = partial + 64;                    // E

    hipMemsetAsync(count, 0, (size_t)N * sizeof(int), stream);

    transpose_w_kernel<<<(C * C + 255) / 256, 256, 0, stream>>>(W1, W2, W1T, W2T);

    histogram_kernel<<<(E + 255) / 256, 256, 0, stream>>>(idx, count, E);
    scan_partials_kernel<<<nchunks, 256, 0, stream>>>(count, partial, N);
    scan_chunkbase_kernel<<<1, 64, 0, stream>>>(partial, base, nchunks, N);
    scan_apply_kernel<<<nchunks, SCAN_CHUNK, 0, stream>>>(count, partial, base, cursor, N);
    fill_perm_kernel<<<(E + 255) / 256, 256, 0, stream>>>(idx, cursor, perm, E);

    // gather: one atom per 128-thread block
    gather_kernel<<<N, 128, 0, stream>>>(x, rbf, env, perm, base,
                                         Wrbf, brbf, acc, N);

    const int tiles = (N + C - 1) / C;
    mlp_head_kernel<<<tiles, 256, 0, stream>>>(acc, W1T, b1, W2T, b2, W3, b3, out, N);
}

// Round 5
// 377.902 us; speedup vs baseline: 1.6362x; 1.0038x over previous
//
#include <hip/hip_runtime.h>
#include <hip/hip_bf16.h>

#define C 128
#define RBFD 20
#define NATOMS 50000
#define SCAN_CHUNK 1024
#define EDGE_CHUNK 64

// ---------------------------------------------------------------------------
// Kernel 1: setup — transpose W1, W2 into [in][out] AND zero the histogram
// counters (replaces the pathologically slow graph-captured memset node).
// ---------------------------------------------------------------------------
__global__ __launch_bounds__(256) void setup_kernel(
    const float* __restrict__ W1, const float* __restrict__ W2,
    float* __restrict__ W1T, float* __restrict__ W2T,
    int* __restrict__ count, int n)
{
    const int t = blockIdx.x * blockDim.x + threadIdx.x;
    if (t < C * C) {
        int k = t / C;   // in-channel
        int c = t % C;   // out-channel
        W1T[t] = W1[c * C + k];
        W2T[t] = W2[c * C + k];
    }
    for (int i = t; i < n; i += gridDim.x * blockDim.x) count[i] = 0;
}

// ---------------------------------------------------------------------------
// CSR construction: histogram -> hierarchical exclusive scan -> perm fill
// ---------------------------------------------------------------------------
__global__ __launch_bounds__(256) void histogram_kernel(
    const int* __restrict__ idx, int* __restrict__ count, int E)
{
    int e = blockIdx.x * blockDim.x + threadIdx.x;
    if (e < E) atomicAdd(&count[idx[e]], 1);
}

__global__ __launch_bounds__(256) void scan_partials_kernel(
    const int* __restrict__ count, int* __restrict__ partial, int n)
{
    __shared__ int sm[256];
    const int start = blockIdx.x * SCAN_CHUNK;
    int s = 0;
    for (int i = threadIdx.x; i < SCAN_CHUNK; i += 256) {
        int g = start + i;
        if (g < n) s += count[g];
    }
    sm[threadIdx.x] = s;
    __syncthreads();
    for (int off = 128; off > 0; off >>= 1) {
        if (threadIdx.x < off) sm[threadIdx.x] += sm[threadIdx.x + off];
        __syncthreads();
    }
    if (threadIdx.x == 0) partial[blockIdx.x] = sm[0];
}

__global__ void scan_chunkbase_kernel(int* __restrict__ partial,
                                      int* __restrict__ base,
                                      int nchunks, int n)
{
    if (threadIdx.x == 0 && blockIdx.x == 0) {
        int run = 0;
        for (int k = 0; k < nchunks; ++k) {
            int t = partial[k];
            partial[k] = run;
            run += t;
        }
        base[n] = run;
    }
}

__global__ __launch_bounds__(1024) void scan_apply_kernel(
    const int* __restrict__ count, const int* __restrict__ chunk_base,
    int* __restrict__ base, int* __restrict__ cursor, int n)
{
    __shared__ int sm[SCAN_CHUNK];
    const int t = threadIdx.x;
    const int i = blockIdx.x * SCAN_CHUNK + t;
    int v = (i < n) ? count[i] : 0;
    sm[t] = v;
    __syncthreads();
    for (int off = 1; off < SCAN_CHUNK; off <<= 1) {
        int tmp = (t >= off) ? sm[t - off] : 0;
        __syncthreads();
        sm[t] += tmp;
        __syncthreads();
    }
    if (i < n) {
        int excl = sm[t] - v + chunk_base[blockIdx.x];
        base[i] = excl;
        cursor[i] = excl;
    }
}

__global__ __launch_bounds__(256) void fill_perm_kernel(
    const int* __restrict__ idx, int* __restrict__ cursor,
    int* __restrict__ perm, int E)
{
    int e = blockIdx.x * blockDim.x + threadIdx.x;
    if (e < E) {
        int a = idx[e];
        int pos = atomicAdd(&cursor[a], 1);
        perm[pos] = e;
    }
}

// ---------------------------------------------------------------------------
// Gather kernel: one atom per 128-thread block (thread = channel).
// LDS-staged edge chunk + 4-wide predicated unroll (unchanged from round 4).
// ---------------------------------------------------------------------------
__device__ __forceinline__ float rbf_dot(const float4* __restrict__ r4,
                                         const float* __restrict__ w,
                                         float bias)
{
    float4 rv0 = r4[0], rv1 = r4[1], rv2 = r4[2], rv3 = r4[3], rv4 = r4[4];
    float f = bias;
    f = fmaf(rv0.x, w[0], f);  f = fmaf(rv0.y, w[1], f);
    f = fmaf(rv0.z, w[2], f);  f = fmaf(rv0.w, w[3], f);
    f = fmaf(rv1.x, w[4], f);  f = fmaf(rv1.y, w[5], f);
    f = fmaf(rv1.z, w[6], f);  f = fmaf(rv1.w, w[7], f);
    f = fmaf(rv2.x, w[8], f);  f = fmaf(rv2.y, w[9], f);
    f = fmaf(rv2.z, w[10], f); f = fmaf(rv2.w, w[11], f);
    f = fmaf(rv3.x, w[12], f); f = fmaf(rv3.y, w[13], f);
    f = fmaf(rv3.z, w[14], f); f = fmaf(rv3.w, w[15], f);
    f = fmaf(rv4.x, w[16], f); f = fmaf(rv4.y, w[17], f);
    f = fmaf(rv4.z, w[18], f); f = fmaf(rv4.w, w[19], f);
    return f;
}

__global__ __launch_bounds__(128) void gather_kernel(
    const float* __restrict__ x,       // [E][C]
    const float* __restrict__ rbf,     // [E][RBFD]
    const float* __restrict__ env,     // [E]
    const int*   __restrict__ perm,    // [E]
    const int*   __restrict__ base,    // [N+1]
    const float* __restrict__ Wrbf,    // [C][RBFD]
    const float* __restrict__ brbf,    // [C]
    float* __restrict__ acc,           // [N][C]
    int natoms)
{
    __shared__ int   e_s[EDGE_CHUNK];
    __shared__ float env_s[EDGE_CHUNK];

    const int tid = threadIdx.x;      // 0..127, = channel
    const int a   = blockIdx.x;
    if (a >= natoms) return;

    float w[RBFD];
#pragma unroll
    for (int r = 0; r < RBFD; ++r) w[r] = Wrbf[tid * RBFD + r];
    const float bias = brbf[tid];

    const int s0 = base[a], s1 = base[a + 1];
    float sum = 0.0f;

    for (int chunk = s0; chunk < s1; chunk += EDGE_CHUNK) {
        const int cnt = min(EDGE_CHUNK, s1 - chunk);
        __syncthreads();
        if (tid < cnt) {
            const int e = perm[chunk + tid];
            e_s[tid]   = e;
            env_s[tid] = env[e];
        }
        __syncthreads();

        for (int r = 0; r < cnt; r += 4) {
            int   rr0 = r,     rr1 = r + 1, rr2 = r + 2, rr3 = r + 3;
            bool  ok1 = rr1 < cnt, ok2 = rr2 < cnt, ok3 = rr3 < cnt;
            int   e0 = e_s[rr0];
            int   e1 = e_s[ok1 ? rr1 : 0];
            int   e2 = e_s[ok2 ? rr2 : 0];
            int   e3 = e_s[ok3 ? rr3 : 0];
            float m0 = env_s[rr0];
            float m1 = ok1 ? env_s[rr1] : 0.0f;
            float m2 = ok2 ? env_s[rr2] : 0.0f;
            float m3 = ok3 ? env_s[rr3] : 0.0f;

            const float4* r40 = reinterpret_cast<const float4*>(rbf + (size_t)e0 * RBFD);
            const float4* r41 = reinterpret_cast<const float4*>(rbf + (size_t)e1 * RBFD);
            const float4* r42 = reinterpret_cast<const float4*>(rbf + (size_t)e2 * RBFD);
            const float4* r43 = reinterpret_cast<const float4*>(rbf + (size_t)e3 * RBFD);

            const float x0 = x[(size_t)e0 * C + tid];
            const float x1 = x[(size_t)e1 * C + tid];
            const float x2 = x[(size_t)e2 * C + tid];
            const float x3 = x[(size_t)e3 * C + tid];

            const float f0 = rbf_dot(r40, w, bias);
            const float f1 = rbf_dot(r41, w, bias);
            const float f2 = rbf_dot(r42, w, bias);
            const float f3 = rbf_dot(r43, w, bias);

            sum = fmaf(f0 * m0, x0, sum);
            sum = fmaf(f1 * m1, x1, sum);
            sum = fmaf(f2 * m2, x2, sum);
            sum = fmaf(f3 * m3, x3, sum);
        }
    }
    acc[(size_t)a * C + tid] = sum;
}

// ---------------------------------------------------------------------------
// Fused MLP head (unchanged).
// ---------------------------------------------------------------------------
__device__ __forceinline__ float silu_f(float v) {
    return v * (1.0f / (1.0f + __expf(-v)));
}

__global__ __launch_bounds__(256) void mlp_head_kernel(
    const float* __restrict__ acc,   // [N][C]
    const float* __restrict__ W1T,   // [C][C]  (k-major)
    const float* __restrict__ b1,    // [C]
    const float* __restrict__ W2T,   // [C][C]
    const float* __restrict__ b2,    // [C]
    const float* __restrict__ W3,    // [1][C]
    const float* __restrict__ b3,    // [1]
    float* __restrict__ out,         // [N]
    int natoms)
{
    __shared__ float As[C][C + 1];

    const int tid = threadIdx.x;
    const int a0  = blockIdx.x * C;
    const int tc  = tid & 15;
    const int ta  = tid >> 4;
    const int abase = ta * 8;
    const int cbase = tc * 8;

    {
        const int sub = tid >> 7;
        const int k   = tid & 127;
        for (int pair = 0; pair < 64; ++pair) {
            const int al = pair * 2 + sub;
            const int a  = a0 + al;
            float v = (a < natoms) ? acc[(size_t)a * C + k] : 0.0f;
            As[k][al] = v;
        }
    }
    __syncthreads();

    float r[8][8];

    // layer 1
#pragma unroll
    for (int i = 0; i < 8; ++i)
#pragma unroll
        for (int j = 0; j < 8; ++j) r[i][j] = 0.0f;

#pragma unroll 2
    for (int k = 0; k < C; ++k) {
        float4 bq0 = *reinterpret_cast<const float4*>(W1T + k * C + cbase);
        float4 bq1 = *reinterpret_cast<const float4*>(W1T + k * C + cbase + 4);
        float bv[8] = {bq0.x, bq0.y, bq0.z, bq0.w, bq1.x, bq1.y, bq1.z, bq1.w};
        float av[8];
#pragma unroll
        for (int i = 0; i < 8; ++i) av[i] = As[k][abase + i];
#pragma unroll
        for (int i = 0; i < 8; ++i)
#pragma unroll
            for (int j = 0; j < 8; ++j) r[i][j] = fmaf(av[i], bv[j], r[i][j]);
    }

    __syncthreads();
    {
        float bb[8];
#pragma unroll
        for (int j = 0; j < 8; ++j) bb[j] = b1[cbase + j];
#pragma unroll
        for (int i = 0; i < 8; ++i)
#pragma unroll
            for (int j = 0; j < 8; ++j)
                As[cbase + j][abase + i] = silu_f(r[i][j] + bb[j]);
    }
    __syncthreads();

    // layer 2
#pragma unroll
    for (int i = 0; i < 8; ++i)
#pragma unroll
        for (int j = 0; j < 8; ++j) r[i][j] = 0.0f;

#pragma unroll 2
    for (int k = 0; k < C; ++k) {
        float4 bq0 = *reinterpret_cast<const float4*>(W2T + k * C + cbase);
        float4 bq1 = *reinterpret_cast<const float4*>(W2T + k * C + cbase + 4);
        float bv[8] = {bq0.x, bq0.y, bq0.z, bq0.w, bq1.x, bq1.y, bq1.z, bq1.w};
        float av[8];
#pragma unroll
        for (int i = 0; i < 8; ++i) av[i] = As[k][abase + i];
#pragma unroll
        for (int i = 0; i < 8; ++i)
#pragma unroll
            for (int j = 0; j < 8; ++j) r[i][j] = fmaf(av[i], bv[j], r[i][j]);
    }

    __syncthreads();

    // final: silu(.. + b2) . W3
    {
        float bb[8], w3v[8];
#pragma unroll
        for (int j = 0; j < 8; ++j) bb[j] = b2[cbase + j];
        float4 wq0 = *reinterpret_cast<const float4*>(W3 + cbase);
        float4 wq1 = *reinterpret_cast<const float4*>(W3 + cbase + 4);
        w3v[0]=wq0.x; w3v[1]=wq0.y; w3v[2]=wq0.z; w3v[3]=wq0.w;
        w3v[4]=wq1.x; w3v[5]=wq1.y; w3v[6]=wq1.z; w3v[7]=wq1.w;

#pragma unroll
        for (int i = 0; i < 8; ++i) {
            float p = 0.0f;
#pragma unroll
            for (int j = 0; j < 8; ++j)
                p = fmaf(silu_f(r[i][j] + bb[j]), w3v[j], p);
            As[abase + i][tc] = p;
        }
    }
    __syncthreads();

    if (tid < C) {
        const int a = a0 + tid;
        if (a < natoms) {
            float s = 0.0f;
#pragma unroll
            for (int t = 0; t < 16; ++t) s += As[tid][t];
            out[a] = s + b3[0];
        }
    }
}

// ---------------------------------------------------------------------------
extern "C" void kernel_launch(void* const* d_in, const int* in_sizes, int n_in,
                              void* d_out, int out_size, void* d_ws, size_t ws_size,
                              hipStream_t stream) {
    const float* x      = (const float*)d_in[0];
    const float* rbf    = (const float*)d_in[1];
    const float* env    = (const float*)d_in[2];
    const int*   idx    = (const int*)  d_in[3];
    const float* Wrbf   = (const float*)d_in[5];
    const float* brbf   = (const float*)d_in[6];
    const float* W1     = (const float*)d_in[7];
    const float* b1     = (const float*)d_in[8];
    const float* W2     = (const float*)d_in[9];
    const float* b2     = (const float*)d_in[10];
    const float* W3     = (const float*)d_in[11];
    const float* b3     = (const float*)d_in[12];
    float*       out    = (float*)d_out;

    const int E = in_sizes[0] / C;        // 800000
    const int N = NATOMS;                 // 50000
    const int nchunks = (N + SCAN_CHUNK - 1) / SCAN_CHUNK;   // 49

    // workspace layout
    float* acc     = (float*)d_ws;                    // N*C
    float* W1T     = acc + (size_t)N * C;             // C*C
    float* W2T     = W1T + C * C;                     // C*C
    int*   count   = (int*)(W2T + C * C);             // N
    int*   base    = count + N;                       // N+1
    int*   cursor  = base + (N + 1);                  // N
    int*   partial = cursor + N;                      // 64
    int*   perm    = partial + 64;                    // E

    // setup: transpose weights + zero histogram counters (NO memset node)
    setup_kernel<<<(N + 255) / 256, 256, 0, stream>>>(W1, W2, W1T, W2T, count, N);

    histogram_kernel<<<(E + 255) / 256, 256, 0, stream>>>(idx, count, E);
    scan_partials_kernel<<<nchunks, 256, 0, stream>>>(count, partial, N);
    scan_chunkbase_kernel<<<1, 64, 0, stream>>>(partial, base, nchunks, N);
    scan_apply_kernel<<<nchunks, SCAN_CHUNK, 0, stream>>>(count, partial, base, cursor, N);
    fill_perm_kernel<<<(E + 255) / 256, 256, 0, stream>>>(idx, cursor, perm, E);

    // gather: one atom per 128-thread block
    gather_kernel<<<N, 128, 0, stream>>>(x, rbf, env, perm, base,
                                         Wrbf, brbf, acc, N);

    const int tiles = (N + C - 1) / C;
    mlp_head_kernel<<<tiles, 256, 0, stream>>>(acc, W1T, b1, W2T, b2, W3, b3, out, N);
}